// Round 1
// baseline (790.871 us; speedup 1.0000x reference)
//
#include <hip/hip_runtime.h>
#include <math.h>

// Problem constants (from reference setup_inputs)
#define BB   16
#define NNpt 4096
#define MM   1024
#define C1c  128
#define C2c  256
#define CINc 384
#define H1c  256
#define H2c  128
#define TN   64     // n tile per block
#define TM   32     // m / k chunk
#define EPSF 1e-8f

#define LDA  64     // s_a row stride (inv tile [m][n])
#define LDW  260    // s_w row stride (p2 [m][c] / W1t [k][o1]), padded
#define LDW2 132    // W2t [k][o2] stride, padded
#define LDX  68     // s_x row stride ([k][n]), padded

// Fully fused: inverse-distance interp (unnormalized GEMM + row-sum) ->
// normalize -> concat with points1 -> W1+relu -> W2+relu -> out.
// fp32 baseline, 8x8 register tiles, LDS ~51 KB.
__global__ __launch_bounds__(256, 2) void fp_fused(
    const float* __restrict__ xyz1, const float* __restrict__ xyz2,
    const float* __restrict__ p1,   const float* __restrict__ p2,
    const float* __restrict__ W1,   const float* __restrict__ b1v,
    const float* __restrict__ W2,   const float* __restrict__ b2v,
    float* __restrict__ out)
{
    __shared__ float s_a[TM * LDA];        // 2048 f: inv tile [m][n]
    __shared__ float s_w[TM * LDW];        // 8320 f: p2 [m][c] / W1t [k][o1] / W2t [k][o2]
    __shared__ float s_x[TM * LDX];        // 2176 f: x chunk [k][n] / h chunk [o1][n]
    __shared__ float s_red[4 * 64];        // inv row-sum partials

    const int tid = threadIdx.x;
    const int b   = blockIdx.y;
    const int n0  = blockIdx.x * TN;

    const int tc8 = tid & 31;   // phase A: c-group (c = tc8*8+i); phase B: o1-group
    const int tn8 = tid >> 5;   // n-group  (n = tn8*8+j) — same in all phases
    const int an  = tid & 63;   // inv-gen: this thread's n row
    const int mg  = tid >> 6;   // inv-gen: m sub-group 0..3

    // this thread's xyz1 point (for inv generation)
    const float x1x = xyz1[((size_t)b * NNpt + n0 + an) * 3 + 0];
    const float x1y = xyz1[((size_t)b * NNpt + n0 + an) * 3 + 1];
    const float x1z = xyz1[((size_t)b * NNpt + n0 + an) * 3 + 2];

    const float* __restrict__ p2b = p2   + (size_t)b * C2c * MM;
    const float* __restrict__ z2b = xyz2 + (size_t)b * MM * 3;

    // ---------------- Phase A: U[c][n] = sum_m inv(n,m) * p2[c][m]; S[n] = sum_m inv ----
    float acc[8][8];
    #pragma unroll
    for (int i = 0; i < 8; ++i)
        #pragma unroll
        for (int j = 0; j < 8; ++j) acc[i][j] = 0.f;
    float ssum = 0.f;

    for (int m0 = 0; m0 < MM; m0 += TM) {
        __syncthreads();   // previous GEMM done reading s_a / s_w
        // stage p2 chunk -> s_w[m][c]  (coalesced global reads along m)
        {
            const int tm = tid & 31, tcg = tid >> 5;
            const float* src = p2b + m0 + tm;
            #pragma unroll
            for (int j = 0; j < 32; ++j) {
                const int c = tcg + 8 * j;
                s_w[tm * LDW + c] = src[(size_t)c * MM];
            }
        }
        // generate inv tile -> s_a[m][n]; accumulate row-sum partial
        #pragma unroll
        for (int i = 0; i < 8; ++i) {
            const int m = m0 + mg * 8 + i;
            const float dx = x1x - z2b[m * 3 + 0];
            const float dy = x1y - z2b[m * 3 + 1];
            const float dz = x1z - z2b[m * 3 + 2];
            const float d2 = dx * dx + dy * dy + dz * dz;
            const float inv = 1.0f / (sqrtf(d2) + EPSF);
            s_a[(mg * 8 + i) * LDA + an] = inv;
            ssum += inv;
        }
        __syncthreads();
        // 64x256 GEMM micro-step over 32 m
        const float* pa = s_a + tn8 * 8;
        const float* pb = s_w + tc8 * 8;
        #pragma unroll 8
        for (int m = 0; m < TM; ++m) {
            float av[8], bv[8];
            *(float4*)&av[0] = *(const float4*)(pa + m * LDA);
            *(float4*)&av[4] = *(const float4*)(pa + m * LDA + 4);
            *(float4*)&bv[0] = *(const float4*)(pb + m * LDW);
            *(float4*)&bv[4] = *(const float4*)(pb + m * LDW + 4);
            #pragma unroll
            for (int i = 0; i < 8; ++i)
                #pragma unroll
                for (int j = 0; j < 8; ++j)
                    acc[i][j] = fmaf(bv[i], av[j], acc[i][j]);
        }
    }

    // reduce S[n] over the 4 mg partials; each thread builds reciprocal for its 8 n
    s_red[mg * 64 + an] = ssum;
    __syncthreads();
    float rn[8];
    #pragma unroll
    for (int j = 0; j < 8; ++j) {
        const int n = tn8 * 8 + j;
        rn[j] = 1.0f / (s_red[n] + s_red[64 + n] + s_red[128 + n] + s_red[192 + n]);
    }

    // ---------------- Phase B: h = relu(W1 @ concat(p1, interp) + b1) ------------------
    float hacc[8][8];
    #pragma unroll
    for (int i = 0; i < 8; ++i)
        #pragma unroll
        for (int j = 0; j < 8; ++j) hacc[i][j] = 0.f;

    const float* __restrict__ p1b = p1 + (size_t)b * C1c * NNpt + n0;

    for (int kc = 0; kc < 12; ++kc) {   // 12 chunks of 32 k: 0..3 = points1, 4..11 = interp
        __syncthreads();
        if (kc < 4) {
            const int nn_ = tid & 63, kkg = tid >> 6;
            #pragma unroll
            for (int i = 0; i < 8; ++i) {
                const int kk = kkg * 8 + i;
                s_x[kk * LDX + nn_] = p1b[(size_t)(kc * 32 + kk) * NNpt + nn_];
            }
        } else {
            const int cg = tc8 - (kc - 4) * 4;   // which threads own this interp c-chunk
            if (cg >= 0 && cg < 4) {
                #pragma unroll
                for (int i = 0; i < 8; ++i)
                    #pragma unroll
                    for (int j = 0; j < 8; ++j)
                        s_x[(cg * 8 + i) * LDX + tn8 * 8 + j] = acc[i][j] * rn[j];
            }
        }
        // stage W1 chunk transposed -> s_w[kk][o1]
        {
            const int kk = tid & 31, og = tid >> 5;
            const float* src = W1 + (size_t)kc * 32 + kk;
            #pragma unroll
            for (int j = 0; j < 32; ++j) {
                const int o = og + 8 * j;
                s_w[kk * LDW + o] = src[(size_t)o * CINc];
            }
        }
        __syncthreads();
        const float* pa = s_w + tc8 * 8;   // o1 fragment
        const float* pb = s_x + tn8 * 8;   // n fragment
        #pragma unroll 8
        for (int k = 0; k < TM; ++k) {
            float av[8], bv[8];
            *(float4*)&av[0] = *(const float4*)(pa + k * LDW);
            *(float4*)&av[4] = *(const float4*)(pa + k * LDW + 4);
            *(float4*)&bv[0] = *(const float4*)(pb + k * LDX);
            *(float4*)&bv[4] = *(const float4*)(pb + k * LDX + 4);
            #pragma unroll
            for (int i = 0; i < 8; ++i)
                #pragma unroll
                for (int j = 0; j < 8; ++j)
                    hacc[i][j] = fmaf(av[i], bv[j], hacc[i][j]);
        }
    }
    // bias + relu (in place)
    {
        float bb[8];
        *(float4*)&bb[0] = *(const float4*)(b1v + tc8 * 8);
        *(float4*)&bb[4] = *(const float4*)(b1v + tc8 * 8 + 4);
        #pragma unroll
        for (int i = 0; i < 8; ++i)
            #pragma unroll
            for (int j = 0; j < 8; ++j)
                hacc[i][j] = fmaxf(hacc[i][j] + bb[i], 0.f);
    }

    // ---------------- Phase C: out = relu(W2 @ h + b2) ---------------------------------
    float oacc[4][8];
    #pragma unroll
    for (int i = 0; i < 4; ++i)
        #pragma unroll
        for (int j = 0; j < 8; ++j) oacc[i][j] = 0.f;
    const int tq = tid & 31;   // o2 = tq*4 + i

    for (int oc = 0; oc < 8; ++oc) {   // 8 chunks of 32 o1
        __syncthreads();
        const int hg = tc8 - oc * 4;   // owners of this h chunk
        if (hg >= 0 && hg < 4) {
            #pragma unroll
            for (int i = 0; i < 8; ++i)
                #pragma unroll
                for (int j = 0; j < 8; ++j)
                    s_x[(hg * 8 + i) * LDX + tn8 * 8 + j] = hacc[i][j];
        }
        // stage W2 chunk transposed -> s_w[kk][o2]
        {
            const int kk = tid & 31, og = tid >> 5;
            const float* src = W2 + (size_t)oc * 32 + kk;
            #pragma unroll
            for (int j = 0; j < 16; ++j) {
                const int o = og + 8 * j;
                s_w[kk * LDW2 + o] = src[(size_t)o * H1c];
            }
        }
        __syncthreads();
        const float* pa = s_w + tq * 4;
        const float* pb = s_x + tn8 * 8;
        #pragma unroll 8
        for (int k = 0; k < TM; ++k) {
            float av[4], bv[8];
            *(float4*)&av[0] = *(const float4*)(pa + k * LDW2);
            *(float4*)&bv[0] = *(const float4*)(pb + k * LDX);
            *(float4*)&bv[4] = *(const float4*)(pb + k * LDX + 4);
            #pragma unroll
            for (int i = 0; i < 4; ++i)
                #pragma unroll
                for (int j = 0; j < 8; ++j)
                    oacc[i][j] = fmaf(av[i], bv[j], oacc[i][j]);
        }
    }

    // epilogue: bias + relu + store
    {
        float bb2[4];
        *(float4*)&bb2[0] = *(const float4*)(b2v + tq * 4);
        float* ob = out + (size_t)b * H2c * NNpt + n0 + tn8 * 8;
        #pragma unroll
        for (int i = 0; i < 4; ++i) {
            float4 v0, v1;
            v0.x = fmaxf(oacc[i][0] + bb2[i], 0.f);
            v0.y = fmaxf(oacc[i][1] + bb2[i], 0.f);
            v0.z = fmaxf(oacc[i][2] + bb2[i], 0.f);
            v0.w = fmaxf(oacc[i][3] + bb2[i], 0.f);
            v1.x = fmaxf(oacc[i][4] + bb2[i], 0.f);
            v1.y = fmaxf(oacc[i][5] + bb2[i], 0.f);
            v1.z = fmaxf(oacc[i][6] + bb2[i], 0.f);
            v1.w = fmaxf(oacc[i][7] + bb2[i], 0.f);
            *(float4*)(ob + (size_t)(tq * 4 + i) * NNpt)     = v0;
            *(float4*)(ob + (size_t)(tq * 4 + i) * NNpt + 4) = v1;
        }
    }
}

extern "C" void kernel_launch(void* const* d_in, const int* in_sizes, int n_in,
                              void* d_out, int out_size, void* d_ws, size_t ws_size,
                              hipStream_t stream) {
    const float* xyz1 = (const float*)d_in[0];
    const float* xyz2 = (const float*)d_in[1];
    const float* p1   = (const float*)d_in[2];
    const float* p2   = (const float*)d_in[3];
    const float* W1   = (const float*)d_in[4];
    const float* b1   = (const float*)d_in[5];
    const float* W2   = (const float*)d_in[6];
    const float* b2   = (const float*)d_in[7];
    float* out = (float*)d_out;

    dim3 grid(NNpt / TN, BB);   // 64 x 16 = 1024 blocks
    dim3 block(256);
    fp_fused<<<grid, block, 0, stream>>>(xyz1, xyz2, p1, p2, W1, b1, W2, b2, out);
}

// Round 2
// 283.905 us; speedup vs baseline: 2.7857x; 2.7857x over previous
//
#include <hip/hip_runtime.h>
#include <math.h>

// Problem constants (from reference setup_inputs)
#define BBATCH 16
#define NPTS   4096
#define MPTS   1024
#define C1c    128
#define C2c    256
#define CINc   384
#define H1c    256
#define H2c    128
#define TN     64

typedef _Float16 f16x8 __attribute__((ext_vector_type(8)));
typedef _Float16 f16x4 __attribute__((ext_vector_type(4)));
typedef float    f32x4 __attribute__((ext_vector_type(4)));

#define LDB  40   // s_B row stride (f16): [64 n][32 k] inv chunk (80 B rows, 20-bank rotation)
#define LDXc 408  // s_X row stride (f16): [64 n][384 k] x = concat(p1, interp) (816 B, 6-bank rot)
#define LDH  264  // s_H row stride (f16): [64 n][256 k] h (528 B, 4-bank rot)

__device__ __forceinline__ f16x8 cvt8(const float4 a, const float4 b) {
    f16x8 r;
    r[0] = (_Float16)a.x; r[1] = (_Float16)a.y; r[2] = (_Float16)a.z; r[3] = (_Float16)a.w;
    r[4] = (_Float16)b.x; r[5] = (_Float16)b.y; r[6] = (_Float16)b.z; r[7] = (_Float16)b.w;
    return r;
}

// Fully fused fp16-MFMA version:
//   Phase A: U[c][n] = sum_m p2[c][m] * inv[m][n]  (K=1024), S[n] = sum_m inv
//   Phase B: h = relu(W1 @ concat(p1, U/S) + b1)   (K=384)
//   Phase C: out = relu(W2 @ h + b2)               (K=256)
// A-operands (p2/W1/W2) direct from global (k-contiguous) + cvt to f16 frags.
// B-operands through LDS in [n][k] layout. 16x16x32 f16 MFMA, fp32 accum.
__global__ __launch_bounds__(256, 2) void fp_mfma(
    const float* __restrict__ xyz1, const float* __restrict__ xyz2,
    const float* __restrict__ p1,   const float* __restrict__ p2,
    const float* __restrict__ W1,   const float* __restrict__ b1v,
    const float* __restrict__ W2,   const float* __restrict__ b2v,
    float* __restrict__ out)
{
    __shared__ __align__(16) char      s_buf[64 * LDXc * 2];   // 52224 B: xyz2 / X / H
    __shared__ __align__(16) _Float16  s_B[2][64 * LDB];       // 10240 B: inv chunks (dbuf)
    __shared__ float s_red[256];
    __shared__ float s_recip[64];

    float*    s_xyz2 = (float*)s_buf;        // phase A: [1024][3] fp32
    _Float16* s_X    = (_Float16*)s_buf;     // phase B: [64][LDXc]
    _Float16* s_H    = (_Float16*)s_buf;     // phase C: [64][LDH]

    const int tid  = threadIdx.x;
    const int w    = tid >> 6;    // wave 0..3
    const int L    = tid & 63;    // lane
    const int quad = L >> 4;      // 0..3
    const int l16  = L & 15;

    // XCD swizzle: each XCD (id%8) sees only 2 batches -> p2 working set 2 MB < 4 MB L2
    const int id = blockIdx.x;
    const int b  = (id & 7) * 2 + ((id >> 3) & 1);
    const int n0 = (id >> 4) * TN;

    const float* __restrict__ p2b = p2   + (size_t)b * C2c * MPTS;
    const float* __restrict__ z2b = xyz2 + (size_t)b * MPTS * 3;

    // stage xyz2 for this batch (12 KB)
    for (int i = tid; i < MPTS * 3; i += 256) s_xyz2[i] = z2b[i];

    // this thread's query point (n = L); thread handles k-cols [w*8, w*8+8) of each inv chunk
    const float x1x = xyz1[((size_t)b * NPTS + n0 + L) * 3 + 0];
    const float x1y = xyz1[((size_t)b * NPTS + n0 + L) * 3 + 1];
    const float x1z = xyz1[((size_t)b * NPTS + n0 + L) * 3 + 2];

    // ---------------- Phase A: interp GEMM, K = 1024, 32 k-steps of 32 ----------------
    f32x4 acc[4][4];
    #pragma unroll
    for (int ct = 0; ct < 4; ++ct)
        #pragma unroll
        for (int nt = 0; nt < 4; ++nt)
            acc[ct][nt] = (f32x4){0.f, 0.f, 0.f, 0.f};

    // A (p2) global base: row = w*64 + ct*16 + l16, k offset quad*8
    const float* aptr = p2b + (size_t)(w * 64 + l16) * MPTS + quad * 8;

    float4 pf[2][4][2];
    #pragma unroll
    for (int ct = 0; ct < 4; ++ct) {
        const float* ap = aptr + ct * (16 * MPTS);
        pf[0][ct][0] = *(const float4*)(ap);
        pf[0][ct][1] = *(const float4*)(ap + 4);
    }

    float ssum = 0.f;
    __syncthreads();   // xyz2 staged

    #pragma unroll 2
    for (int s = 0; s < 32; ++s) {
        const int cur = s & 1;
        // prefetch next A chunk (latency covered by inv-gen VALU below)
        if (s + 1 < 32) {
            #pragma unroll
            for (int ct = 0; ct < 4; ++ct) {
                const float* ap = aptr + ct * (16 * MPTS) + (s + 1) * 32;
                pf[cur ^ 1][ct][0] = *(const float4*)(ap);
                pf[cur ^ 1][ct][1] = *(const float4*)(ap + 4);
            }
        }
        // generate inv chunk: all lanes of wave w read same 8 xyz2 pts (broadcast)
        {
            const float* zc = s_xyz2 + (s * 32 + w * 8) * 3;
            f16x8 iv;
            #pragma unroll
            for (int i = 0; i < 8; ++i) {
                const float dx = x1x - zc[i * 3 + 0];
                const float dy = x1y - zc[i * 3 + 1];
                const float dz = x1z - zc[i * 3 + 2];
                const float d2 = fmaf(dx, dx, fmaf(dy, dy, dz * dz)) + 1e-12f;
                const float inv = __builtin_amdgcn_rsqf(d2);   // == 1/(dist+1e-8) to ~1e-5 rel
                ssum += inv;
                iv[i] = (_Float16)inv;
            }
            *(f16x8*)(&s_B[cur][L * LDB + w * 8]) = iv;
        }
        // convert current A prefetch to frags
        f16x8 af[4];
        #pragma unroll
        for (int ct = 0; ct < 4; ++ct) af[ct] = cvt8(pf[cur][ct][0], pf[cur][ct][1]);

        __syncthreads();   // inv chunk visible; dbuf makes single barrier safe

        #pragma unroll
        for (int nt = 0; nt < 4; ++nt) {
            const f16x8 bf = *(const f16x8*)(&s_B[cur][(nt * 16 + l16) * LDB + quad * 8]);
            #pragma unroll
            for (int ct = 0; ct < 4; ++ct)
                acc[ct][nt] = __builtin_amdgcn_mfma_f32_16x16x32_f16(af[ct], bf, acc[ct][nt], 0, 0, 0);
        }
    }

    // S[n] reduction across the 4 waves' partials
    __syncthreads();
    s_red[tid] = ssum;
    __syncthreads();
    if (tid < 64)
        s_recip[tid] = 1.0f / (s_red[tid] + s_red[tid + 64] + s_red[tid + 128] + s_red[tid + 192]);

    // p1 staging -> s_X[n][c], c in [0,128): thread n=L, c-range per wave
    {
        const float* p1b = p1 + (size_t)b * C1c * NPTS + n0;
        #pragma unroll
        for (int cc = 0; cc < 8; ++cc) {
            const int c = w * 32 + cc * 4;
            f16x4 v;
            v[0] = (_Float16)p1b[(size_t)(c + 0) * NPTS + L];
            v[1] = (_Float16)p1b[(size_t)(c + 1) * NPTS + L];
            v[2] = (_Float16)p1b[(size_t)(c + 2) * NPTS + L];
            v[3] = (_Float16)p1b[(size_t)(c + 3) * NPTS + L];
            *(f16x4*)(&s_X[L * LDXc + c]) = v;
        }
    }
    __syncthreads();   // s_recip ready, p1 staged

    // interp normalize + stage -> s_X[n][128 + c]
    {
        float rcp4[4];
        #pragma unroll
        for (int nt = 0; nt < 4; ++nt) rcp4[nt] = s_recip[nt * 16 + l16];
        #pragma unroll
        for (int ct = 0; ct < 4; ++ct)
            #pragma unroll
            for (int nt = 0; nt < 4; ++nt) {
                const f32x4 v = acc[ct][nt];
                const float r = rcp4[nt];
                f16x4 hv;
                hv[0] = (_Float16)(v[0] * r);
                hv[1] = (_Float16)(v[1] * r);
                hv[2] = (_Float16)(v[2] * r);
                hv[3] = (_Float16)(v[3] * r);
                *(f16x4*)(&s_X[(nt * 16 + l16) * LDXc + 128 + w * 64 + ct * 16 + quad * 4]) = hv;
            }
    }
    __syncthreads();   // x matrix complete

    // ---------------- Phase B: h = relu(W1 @ x + b1), K = 384, 12 chunks ---------------
    f32x4 hacc[4][4];
    #pragma unroll
    for (int ct = 0; ct < 4; ++ct)
        #pragma unroll
        for (int nt = 0; nt < 4; ++nt)
            hacc[ct][nt] = (f32x4){0.f, 0.f, 0.f, 0.f};

    const float* w1p = W1 + (size_t)(w * 64 + l16) * CINc + quad * 8;
    #pragma unroll 2
    for (int kc = 0; kc < 12; ++kc) {
        f16x8 af[4];
        #pragma unroll
        for (int ct = 0; ct < 4; ++ct) {
            const float* ap = w1p + ct * (16 * CINc) + kc * 32;
            af[ct] = cvt8(*(const float4*)(ap), *(const float4*)(ap + 4));
        }
        #pragma unroll
        for (int nt = 0; nt < 4; ++nt) {
            const f16x8 bf = *(const f16x8*)(&s_X[(nt * 16 + l16) * LDXc + kc * 32 + quad * 8]);
            #pragma unroll
            for (int ct = 0; ct < 4; ++ct)
                hacc[ct][nt] = __builtin_amdgcn_mfma_f32_16x16x32_f16(af[ct], bf, hacc[ct][nt], 0, 0, 0);
        }
    }

    __syncthreads();   // all s_X reads done before overlaying s_H

    // bias + relu + stage h -> s_H[n][o1]
    {
        f32x4 bb[4];
        #pragma unroll
        for (int ct = 0; ct < 4; ++ct)
            bb[ct] = *(const f32x4*)(b1v + w * 64 + ct * 16 + quad * 4);
        #pragma unroll
        for (int ct = 0; ct < 4; ++ct)
            #pragma unroll
            for (int nt = 0; nt < 4; ++nt) {
                const f32x4 v = hacc[ct][nt];
                f16x4 hv;
                hv[0] = (_Float16)fmaxf(v[0] + bb[ct][0], 0.f);
                hv[1] = (_Float16)fmaxf(v[1] + bb[ct][1], 0.f);
                hv[2] = (_Float16)fmaxf(v[2] + bb[ct][2], 0.f);
                hv[3] = (_Float16)fmaxf(v[3] + bb[ct][3], 0.f);
                *(f16x4*)(&s_H[(nt * 16 + l16) * LDH + w * 64 + ct * 16 + quad * 4]) = hv;
            }
    }
    __syncthreads();

    // ---------------- Phase C: out = relu(W2 @ h + b2), K = 256, 8 chunks --------------
    f32x4 oacc[2][4];
    #pragma unroll
    for (int ct = 0; ct < 2; ++ct)
        #pragma unroll
        for (int nt = 0; nt < 4; ++nt)
            oacc[ct][nt] = (f32x4){0.f, 0.f, 0.f, 0.f};

    const float* w2p = W2 + (size_t)(w * 32 + l16) * H1c + quad * 8;
    #pragma unroll 2
    for (int oc = 0; oc < 8; ++oc) {
        f16x8 af2[2];
        #pragma unroll
        for (int ct = 0; ct < 2; ++ct) {
            const float* ap = w2p + ct * (16 * H1c) + oc * 32;
            af2[ct] = cvt8(*(const float4*)(ap), *(const float4*)(ap + 4));
        }
        #pragma unroll
        for (int nt = 0; nt < 4; ++nt) {
            const f16x8 bf = *(const f16x8*)(&s_H[(nt * 16 + l16) * LDH + oc * 32 + quad * 8]);
            #pragma unroll
            for (int ct = 0; ct < 2; ++ct)
                oacc[ct][nt] = __builtin_amdgcn_mfma_f32_16x16x32_f16(af2[ct], bf, oacc[ct][nt], 0, 0, 0);
        }
    }

    // epilogue: bias + relu + store
    {
        f32x4 bb2[2];
        #pragma unroll
        for (int ct = 0; ct < 2; ++ct)
            bb2[ct] = *(const f32x4*)(b2v + w * 32 + ct * 16 + quad * 4);
        #pragma unroll
        for (int ct = 0; ct < 2; ++ct)
            #pragma unroll
            for (int nt = 0; nt < 4; ++nt) {
                float* op = out + ((size_t)b * H2c + w * 32 + ct * 16 + quad * 4) * NPTS
                                + n0 + nt * 16 + l16;
                #pragma unroll
                for (int j = 0; j < 4; ++j)
                    op[(size_t)j * NPTS] = fmaxf(oacc[ct][nt][j] + bb2[ct][j], 0.f);
            }
    }
}

extern "C" void kernel_launch(void* const* d_in, const int* in_sizes, int n_in,
                              void* d_out, int out_size, void* d_ws, size_t ws_size,
                              hipStream_t stream) {
    (void)in_sizes; (void)n_in; (void)d_ws; (void)ws_size; (void)out_size;
    const float* xyz1 = (const float*)d_in[0];
    const float* xyz2 = (const float*)d_in[1];
    const float* p1   = (const float*)d_in[2];
    const float* p2   = (const float*)d_in[3];
    const float* W1   = (const float*)d_in[4];
    const float* b1   = (const float*)d_in[5];
    const float* W2   = (const float*)d_in[6];
    const float* b2   = (const float*)d_in[7];
    float* out = (float*)d_out;

    dim3 grid(BBATCH * (NPTS / TN));   // 1024 blocks
    dim3 block(256);
    fp_mfma<<<grid, block, 0, stream>>>(xyz1, xyz2, p1, p2, W1, b1, W2, b2, out);
}

// Round 3
// 198.019 us; speedup vs baseline: 3.9939x; 1.4337x over previous
//
#include <hip/hip_runtime.h>
#include <math.h>

// Problem constants (from reference setup_inputs)
#define BBATCH 16
#define NPTS   4096
#define MPTS   1024
#define C1c    128
#define C2c    256
#define CINc   384
#define H1c    256
#define H2c    128
#define TN     64

typedef _Float16 f16x8 __attribute__((ext_vector_type(8)));
typedef _Float16 f16x4 __attribute__((ext_vector_type(4)));
typedef float    f32x4 __attribute__((ext_vector_type(4)));

#define LDP2 40    // f16 stride per c-row of p2 chunk (80 B: 20-bank rotation, 16B-aligned)
#define LDXc 408   // f16 stride s_X rows [64 n][384 k]
#define LDH  264   // f16 stride s_H rows [64 n][256 k]

// shared-memory union region (bytes)
#define OFF_XYZ2 0                      // 12288 B  [1024][3] f32       (phase A)
#define OFF_P2   12288                  // 2 x 256*LDP2*2 = 40960 B     (phase A)
#define SMEM_BYTES 53248                // also >= s_X 52224, s_H 33792

// ws layout (f16 elements)
#define WS_P2H  0
#define WS_W1H  (BBATCH * C2c * MPTS)            // 4194304
#define WS_W2H  (WS_W1H + H1c * CINc)            // +98304
#define WS_F16_TOTAL (WS_W2H + H2c * H1c)        // 4325376 elems = 8650752 B

// ---------------------------------------------------------------------------
// pre-pass: convert p2 / W1 / W2 to f16 into workspace
__global__ __launch_bounds__(256) void cvt_f16(
    const float* __restrict__ p2, const float* __restrict__ W1,
    const float* __restrict__ W2, _Float16* __restrict__ ws)
{
    const int NP2 = BBATCH * C2c * MPTS / 4;   // 1048576 float4s
    const int NW1 = H1c * CINc / 4;            // 24576
    const int i = blockIdx.x * 256 + threadIdx.x;
    float4 v; _Float16* dst;
    if (i < NP2)            { v = ((const float4*)p2)[i];            dst = ws + WS_P2H + (size_t)i * 4; }
    else if (i < NP2 + NW1) { int j = i - NP2; v = ((const float4*)W1)[j]; dst = ws + WS_W1H + (size_t)j * 4; }
    else                    { int j = i - NP2 - NW1; v = ((const float4*)W2)[j]; dst = ws + WS_W2H + (size_t)j * 4; }
    f16x4 h;
    h[0] = (_Float16)v.x; h[1] = (_Float16)v.y; h[2] = (_Float16)v.z; h[3] = (_Float16)v.w;
    *(f16x4*)dst = h;
}

// ---------------------------------------------------------------------------
// Fused main kernel.
// Phase A: D = U^T[n][c] (+ S[n] via ones-column), A = inv in registers,
//          B = p2 chunk staged in LDS (dbuf, 1 barrier/step).
// Phase B: h = relu(W1 @ concat(p1, U/S) + b1): A = W1 direct global, B = s_X.
// Phase C: out = relu(W2 @ h + b2):             A = W2 direct global, B = s_H.
template <bool F16P>
__global__ __launch_bounds__(256, 3) void fp_mfma2(
    const float* __restrict__ xyz1, const float* __restrict__ xyz2,
    const float* __restrict__ p1,   const float* __restrict__ p2,
    const float* __restrict__ W1,   const float* __restrict__ b1v,
    const float* __restrict__ W2,   const float* __restrict__ b2v,
    const _Float16* __restrict__ p2h, const _Float16* __restrict__ W1h,
    const _Float16* __restrict__ W2h,
    float* __restrict__ out)
{
    __shared__ __align__(16) char smem[SMEM_BYTES];
    float*    s_xyz2 = (float*)(smem + OFF_XYZ2);
    _Float16* s_p2   = (_Float16*)(smem + OFF_P2);
    _Float16* s_X    = (_Float16*)smem;
    _Float16* s_H    = (_Float16*)smem;

    const int tid  = threadIdx.x;
    const int w    = tid >> 6;    // wave 0..3 (owns n-rows w*16..w*16+16 in phase A)
    const int L    = tid & 63;
    const int quad = L >> 4;
    const int l16  = L & 15;

    // XCD swizzle: each XCD sees 2 batches -> p2 working set stays L2-resident
    const int id = blockIdx.x;
    const int b  = (id & 7) * 2 + ((id >> 3) & 1);
    const int n0 = (id >> 4) * TN;

    const float*    __restrict__ p2b  = p2  + (size_t)b * C2c * MPTS;
    const _Float16* __restrict__ p2hb = F16P ? (p2h + (size_t)b * C2c * MPTS) : (const _Float16*)nullptr;
    const float*    __restrict__ z2b  = xyz2 + (size_t)b * MPTS * 3;

    // stage xyz2 (12 KB)
    for (int i = tid; i < MPTS * 3; i += 256) s_xyz2[i] = z2b[i];

    // this lane's query point: n = n0 + w*16 + l16 (A-frag row = l16)
    {
    }
    const float x1x = xyz1[((size_t)b * NPTS + n0 + w * 16 + l16) * 3 + 0];
    const float x1y = xyz1[((size_t)b * NPTS + n0 + w * 16 + l16) * 3 + 1];
    const float x1z = xyz1[((size_t)b * NPTS + n0 + w * 16 + l16) * 3 + 2];

    // ---------------- Phase A ----------------
    f32x4 acc[16];
    #pragma unroll
    for (int ct = 0; ct < 16; ++ct) acc[ct] = (f32x4){0.f, 0.f, 0.f, 0.f};
    f32x4 accS = (f32x4){0.f, 0.f, 0.f, 0.f};

    f16x8 onesv;
    #pragma unroll
    for (int i = 0; i < 8; ++i) onesv[i] = (_Float16)1.0f;

    // staging registers (one chunk ahead)
    f16x8  stg16[4];
    float4 stg32[8];

    if (F16P) {
        #pragma unroll
        for (int r = 0; r < 4; ++r)
            stg16[r] = *(const f16x8*)(p2hb + (size_t)(r * 64 + (tid >> 2)) * MPTS + (tid & 3) * 8);
    } else {
        #pragma unroll
        for (int r = 0; r < 8; ++r)
            stg32[r] = *(const float4*)(p2b + (size_t)(r * 32 + (tid >> 3)) * MPTS + (tid & 7) * 4);
    }

    __syncthreads();   // xyz2 staged

    #pragma unroll 2
    for (int s = 0; s < 32; ++s) {
        _Float16* buf = s_p2 + (s & 1) * (C2c * LDP2);
        // write staged chunk s -> LDS
        if (F16P) {
            #pragma unroll
            for (int r = 0; r < 4; ++r)
                *(f16x8*)(buf + (r * 64 + (tid >> 2)) * LDP2 + (tid & 3) * 8) = stg16[r];
        } else {
            #pragma unroll
            for (int r = 0; r < 8; ++r) {
                const float4 v = stg32[r];
                f16x4 h;
                h[0] = (_Float16)v.x; h[1] = (_Float16)v.y; h[2] = (_Float16)v.z; h[3] = (_Float16)v.w;
                *(f16x4*)(buf + (r * 32 + (tid >> 3)) * LDP2 + (tid & 7) * 4) = h;
            }
        }
        __syncthreads();   // chunk s visible (dbuf: buf s&1^1 free to fill next iter)

        // prefetch chunk s+1 (latency hidden under inv-gen + MFMA)
        if (s + 1 < 32) {
            const int m1 = (s + 1) * 32;
            if (F16P) {
                #pragma unroll
                for (int r = 0; r < 4; ++r)
                    stg16[r] = *(const f16x8*)(p2hb + (size_t)(r * 64 + (tid >> 2)) * MPTS + m1 + (tid & 3) * 8);
            } else {
                #pragma unroll
                for (int r = 0; r < 8; ++r)
                    stg32[r] = *(const float4*)(p2b + (size_t)(r * 32 + (tid >> 3)) * MPTS + m1 + (tid & 7) * 4);
            }
        }

        // inv-gen: 8 values, directly in A-frag layout (row=l16 -> query, k=quad*8+i -> m)
        f32x4 zr[6];
        {
            const float* zp = s_xyz2 + (s * 32 + quad * 8) * 3;
            #pragma unroll
            for (int j = 0; j < 6; ++j) zr[j] = *(const f32x4*)(zp + j * 4);
        }
        const float* zv = (const float*)zr;
        f16x8 af;
        #pragma unroll
        for (int i = 0; i < 8; ++i) {
            const float dx = x1x - zv[3 * i + 0];
            const float dy = x1y - zv[3 * i + 1];
            const float dz = x1z - zv[3 * i + 2];
            const float d2 = fmaf(dx, dx, fmaf(dy, dy, fmaf(dz, dz, 1e-12f)));
            af[i] = (_Float16)__builtin_amdgcn_rsqf(d2);
        }

        // 17 MFMAs: 16 c-tiles + ones-column (row-sum S)
        accS = __builtin_amdgcn_mfma_f32_16x16x32_f16(af, onesv, accS, 0, 0, 0);
        const _Float16* bbase = buf + l16 * LDP2 + quad * 8;
        #pragma unroll
        for (int ct = 0; ct < 16; ++ct) {
            const f16x8 bf = *(const f16x8*)(bbase + ct * (16 * LDP2));
            acc[ct] = __builtin_amdgcn_mfma_f32_16x16x32_f16(af, bf, acc[ct], 0, 0, 0);
        }
    }

    __syncthreads();   // phase A done; smem region about to be reused as s_X

    // normalize reciprocals for this lane's 4 D-rows (n = w*16 + quad*4 + r)
    float rn[4];
    #pragma unroll
    for (int r = 0; r < 4; ++r) rn[r] = 1.0f / accS[r];

    // interp -> s_X[n][128 + c]  (scalar f16 writes, once per block)
    #pragma unroll
    for (int ct = 0; ct < 16; ++ct)
        #pragma unroll
        for (int r = 0; r < 4; ++r)
            s_X[(w * 16 + quad * 4 + r) * LDXc + 128 + ct * 16 + l16] =
                (_Float16)(acc[ct][r] * rn[r]);

    // p1 -> s_X[n][c], c in [0,128)
    {
        const float* p1b = p1 + (size_t)b * C1c * NPTS + n0;
        #pragma unroll
        for (int cc = 0; cc < 8; ++cc) {
            const int c = w * 32 + cc * 4;
            f16x4 v;
            v[0] = (_Float16)p1b[(size_t)(c + 0) * NPTS + L];
            v[1] = (_Float16)p1b[(size_t)(c + 1) * NPTS + L];
            v[2] = (_Float16)p1b[(size_t)(c + 2) * NPTS + L];
            v[3] = (_Float16)p1b[(size_t)(c + 3) * NPTS + L];
            *(f16x4*)(&s_X[L * LDXc + c]) = v;
        }
    }
    __syncthreads();   // x matrix complete

    // ---------------- Phase B: h = relu(W1 @ x + b1), K=384 ----------------
    f32x4 hacc[4][4];
    #pragma unroll
    for (int ct = 0; ct < 4; ++ct)
        #pragma unroll
        for (int nt = 0; nt < 4; ++nt)
            hacc[ct][nt] = (f32x4){0.f, 0.f, 0.f, 0.f};

    #pragma unroll 2
    for (int kc = 0; kc < 12; ++kc) {
        f16x8 af[4];
        if (F16P) {
            const _Float16* wp = W1h + (size_t)(w * 64 + l16) * CINc + kc * 32 + quad * 8;
            #pragma unroll
            for (int ct = 0; ct < 4; ++ct) af[ct] = *(const f16x8*)(wp + ct * (16 * CINc));
        } else {
            const float* wp = W1 + (size_t)(w * 64 + l16) * CINc + kc * 32 + quad * 8;
            #pragma unroll
            for (int ct = 0; ct < 4; ++ct) {
                const float4 a0 = *(const float4*)(wp + ct * (16 * CINc));
                const float4 a1 = *(const float4*)(wp + ct * (16 * CINc) + 4);
                f16x8 h;
                h[0] = (_Float16)a0.x; h[1] = (_Float16)a0.y; h[2] = (_Float16)a0.z; h[3] = (_Float16)a0.w;
                h[4] = (_Float16)a1.x; h[5] = (_Float16)a1.y; h[6] = (_Float16)a1.z; h[7] = (_Float16)a1.w;
                af[ct] = h;
            }
        }
        #pragma unroll
        for (int nt = 0; nt < 4; ++nt) {
            const f16x8 bf = *(const f16x8*)(&s_X[(nt * 16 + l16) * LDXc + kc * 32 + quad * 8]);
            #pragma unroll
            for (int ct = 0; ct < 4; ++ct)
                hacc[ct][nt] = __builtin_amdgcn_mfma_f32_16x16x32_f16(af[ct], bf, hacc[ct][nt], 0, 0, 0);
        }
    }

    __syncthreads();   // all s_X reads done before overlaying s_H

    // bias + relu + stage h -> s_H[n][o1]
    {
        f32x4 bb[4];
        #pragma unroll
        for (int ct = 0; ct < 4; ++ct)
            bb[ct] = *(const f32x4*)(b1v + w * 64 + ct * 16 + quad * 4);
        #pragma unroll
        for (int ct = 0; ct < 4; ++ct)
            #pragma unroll
            for (int nt = 0; nt < 4; ++nt) {
                const f32x4 v = hacc[ct][nt];
                f16x4 hv;
                hv[0] = (_Float16)fmaxf(v[0] + bb[ct][0], 0.f);
                hv[1] = (_Float16)fmaxf(v[1] + bb[ct][1], 0.f);
                hv[2] = (_Float16)fmaxf(v[2] + bb[ct][2], 0.f);
                hv[3] = (_Float16)fmaxf(v[3] + bb[ct][3], 0.f);
                *(f16x4*)(&s_H[(nt * 16 + l16) * LDH + w * 64 + ct * 16 + quad * 4]) = hv;
            }
    }
    __syncthreads();

    // ---------------- Phase C: out = relu(W2 @ h + b2), K=256 ----------------
    f32x4 oacc[2][4];
    #pragma unroll
    for (int ct = 0; ct < 2; ++ct)
        #pragma unroll
        for (int nt = 0; nt < 4; ++nt)
            oacc[ct][nt] = (f32x4){0.f, 0.f, 0.f, 0.f};

    #pragma unroll 2
    for (int oc = 0; oc < 8; ++oc) {
        f16x8 af2[2];
        if (F16P) {
            const _Float16* wp = W2h + (size_t)(w * 32 + l16) * H1c + oc * 32 + quad * 8;
            #pragma unroll
            for (int ct = 0; ct < 2; ++ct) af2[ct] = *(const f16x8*)(wp + ct * (16 * H1c));
        } else {
            const float* wp = W2 + (size_t)(w * 32 + l16) * H1c + oc * 32 + quad * 8;
            #pragma unroll
            for (int ct = 0; ct < 2; ++ct) {
                const float4 a0 = *(const float4*)(wp + ct * (16 * H1c));
                const float4 a1 = *(const float4*)(wp + ct * (16 * H1c) + 4);
                f16x8 h;
                h[0] = (_Float16)a0.x; h[1] = (_Float16)a0.y; h[2] = (_Float16)a0.z; h[3] = (_Float16)a0.w;
                h[4] = (_Float16)a1.x; h[5] = (_Float16)a1.y; h[6] = (_Float16)a1.z; h[7] = (_Float16)a1.w;
                af2[ct] = h;
            }
        }
        #pragma unroll
        for (int nt = 0; nt < 4; ++nt) {
            const f16x8 bf = *(const f16x8*)(&s_H[(nt * 16 + l16) * LDH + oc * 32 + quad * 8]);
            #pragma unroll
            for (int ct = 0; ct < 2; ++ct)
                oacc[ct][nt] = __builtin_amdgcn_mfma_f32_16x16x32_f16(af2[ct], bf, oacc[ct][nt], 0, 0, 0);
        }
    }

    // epilogue: bias + relu + store
    {
        f32x4 bb2[2];
        #pragma unroll
        for (int ct = 0; ct < 2; ++ct)
            bb2[ct] = *(const f32x4*)(b2v + w * 32 + ct * 16 + quad * 4);
        #pragma unroll
        for (int ct = 0; ct < 2; ++ct)
            #pragma unroll
            for (int nt = 0; nt < 4; ++nt) {
                float* op = out + ((size_t)b * H2c + w * 32 + ct * 16 + quad * 4) * NPTS
                                + n0 + nt * 16 + l16;
                #pragma unroll
                for (int j = 0; j < 4; ++j)
                    op[(size_t)j * NPTS] = fmaxf(oacc[ct][nt][j] + bb2[ct][j], 0.f);
            }
    }
}

extern "C" void kernel_launch(void* const* d_in, const int* in_sizes, int n_in,
                              void* d_out, int out_size, void* d_ws, size_t ws_size,
                              hipStream_t stream) {
    (void)in_sizes; (void)n_in; (void)out_size;
    const float* xyz1 = (const float*)d_in[0];
    const float* xyz2 = (const float*)d_in[1];
    const float* p1   = (const float*)d_in[2];
    const float* p2   = (const float*)d_in[3];
    const float* W1   = (const float*)d_in[4];
    const float* b1   = (const float*)d_in[5];
    const float* W2   = (const float*)d_in[6];
    const float* b2   = (const float*)d_in[7];
    float* out = (float*)d_out;

    const bool useh = (ws_size >= (size_t)WS_F16_TOTAL * 2);
    dim3 grid(BBATCH * (NPTS / TN));   // 1024 blocks
    dim3 block(256);
    if (useh) {
        _Float16* ws = (_Float16*)d_ws;
        const int ncvt = (BBATCH * C2c * MPTS + H1c * CINc + H2c * H1c) / 4;  // 1081344
        cvt_f16<<<dim3(ncvt / 256), dim3(256), 0, stream>>>(p2, W1, W2, ws);
        fp_mfma2<true><<<grid, block, 0, stream>>>(xyz1, xyz2, p1, p2, W1, b1, W2, b2,
                                                   ws + WS_P2H, ws + WS_W1H, ws + WS_W2H, out);
    } else {
        fp_mfma2<false><<<grid, block, 0, stream>>>(xyz1, xyz2, p1, p2, W1, b1, W2, b2,
                                                    nullptr, nullptr, nullptr, out);
    }
}